// Round 4
// baseline (298.449 us; speedup 1.0000x reference)
//
#include <hip/hip_runtime.h>
#include <cstdint>

typedef unsigned long long u64;
typedef unsigned int u32;
typedef unsigned short u16;
typedef __attribute__((ext_vector_type(8))) u16 u16x8;
typedef __attribute__((ext_vector_type(4))) u16 u16x4;
typedef __attribute__((ext_vector_type(4))) float f32x4;

#define T_LEN 2048
#define C_DIM 1024
#define H_NUM 16
#define M_ROWS 4096  // B*T
#define MB (1024ull * 1024ull)
#define TAU 2e-4f
#define FCAP 65536u

// bf16 helpers (manual RNE, finite inputs only)
__device__ __forceinline__ u16 f2bf(float f) {
  unsigned u = __builtin_bit_cast(unsigned, f);
  return (u16)((u + 0x7FFFu + ((u >> 16) & 1u)) >> 16);
}
__device__ __forceinline__ float bf2f(u16 u) {
  return __builtin_bit_cast(float, ((unsigned)u) << 16);
}

// async global->LDS, 16B per lane: LDS dest = wave-uniform base + lane*16,
// global src = per-lane pointer (m97 pattern).
__device__ __forceinline__ void async16(u16* lds, const u16* g) {
  __builtin_amdgcn_global_load_lds(
      (const __attribute__((address_space(1))) void*)g,
      (__attribute__((address_space(3))) void*)lds, 16, 0, 0);
}

// ---------------------------------------------------------------------------
// Split fp32 -> (hi,lo) bf16 for x, Wq, Wk, Wv, Wo in one launch.
// ---------------------------------------------------------------------------
__global__ __launch_bounds__(256) void split_all(
    const float* __restrict__ x,  const float* __restrict__ Wq,
    const float* __restrict__ Wk, const float* __restrict__ Wv,
    const float* __restrict__ Wo,
    u16* xh, u16* xl, u16* wqh, u16* wql, u16* wkh, u16* wkl,
    u16* wvh, u16* wvl, u16* woh, u16* wol, u32* flagcnt)
{
  const int i = blockIdx.x * 256 + threadIdx.x;
  if (i == 0) *flagcnt = 0;
  const float* src; u16 *hi, *lo; int off;
  if      (i < 1048576) { src = x;  hi = xh;  lo = xl;  off = i; }
  else if (i < 1310720) { src = Wq; hi = wqh; lo = wql; off = i - 1048576; }
  else if (i < 1572864) { src = Wk; hi = wkh; lo = wkl; off = i - 1310720; }
  else if (i < 1835008) { src = Wv; hi = wvh; lo = wvl; off = i - 1572864; }
  else                  { src = Wo; hi = woh; lo = wol; off = i - 1835008; }
  const float4 v = ((const float4*)src)[off];
  u16x4 h, l;
  float t;
  t = v.x; h[0] = f2bf(t); l[0] = f2bf(t - bf2f(h[0]));
  t = v.y; h[1] = f2bf(t); l[1] = f2bf(t - bf2f(h[1]));
  t = v.z; h[2] = f2bf(t); l[2] = f2bf(t - bf2f(h[2]));
  t = v.w; h[3] = f2bf(t); l[3] = f2bf(t - bf2f(h[3]));
  ((u16x4*)hi)[off] = h;
  ((u16x4*)lo)[off] = l;
}

// ---------------------------------------------------------------------------
// Fused QKV 3-pass split-bf16 MFMA GEMM over N=3072 (sel 0:q, 1:k, 2:v).
// BM=128, BN=64, BK=32, 4 waves. global_load_lds staging (16B/lane) into
// double-buffered linear LDS [buf][sg][row][8]; one vmcnt(0)+barrier per
// K-step (T3 minimum 2-phase). Epilogues as round 3 (verified).
// ---------------------------------------------------------------------------
__global__ __launch_bounds__(256) void mfma_qkv(
    const u16* __restrict__ Ah, const u16* __restrict__ Al,
    const u16* __restrict__ Bqh, const u16* __restrict__ Bql,
    const u16* __restrict__ Bkh, const u16* __restrict__ Bkl,
    const u16* __restrict__ Bvh, const u16* __restrict__ Bvl,
    const float* __restrict__ bq, const float* __restrict__ bk,
    const float* __restrict__ bv,
    u32* __restrict__ pbits, u32* __restrict__ flagcnt,
    u32* __restrict__ flaglist, u16* __restrict__ vT)
{
  __shared__ u16 Ahs[2][4][128][8];   // 16 KB
  __shared__ u16 Als[2][4][128][8];   // 16 KB
  __shared__ u16 Bhs[2][4][64][8];    //  8 KB
  __shared__ u16 Bls[2][4][64][8];    //  8 KB

  const int tid  = threadIdx.x;
  const int lane = tid & 63;
  const int w    = tid >> 6;
  const int wr   = w & 1;
  const int wc   = w >> 1;
  const int bm   = blockIdx.x * 128;
  const int bng  = blockIdx.y * 64;
  const int sel  = bng >> 10;
  const int bnl  = bng & 1023;

  const u16* Bh   = (sel == 0) ? Bqh : (sel == 1) ? Bkh : Bvh;
  const u16* Bl   = (sel == 0) ? Bql : (sel == 1) ? Bkl : Bvl;
  const float* bias = (sel == 0) ? bq : (sel == 1) ? bk : bv;

  f32x4 acc[4][2];
  #pragma unroll
  for (int mf = 0; mf < 4; ++mf)
    #pragma unroll
    for (int nf = 0; nf < 2; ++nf) acc[mf][nf] = (f32x4){0.f, 0.f, 0.f, 0.f};

  // Per-wave staging: wave w owns sg-plane w. 6 async chunks of 1KB:
  // A hi/lo halves 0..63 / 64..127, B hi/lo rows 0..63. Lane l -> row offset l.
#define STAGE(B_, KT)                                                          \
  {                                                                            \
    async16(&Ahs[B_][w][0][0],  &Ah[(size_t)(bm + lane) * 1024 + (KT) + w * 8]);      \
    async16(&Ahs[B_][w][64][0], &Ah[(size_t)(bm + 64 + lane) * 1024 + (KT) + w * 8]); \
    async16(&Als[B_][w][0][0],  &Al[(size_t)(bm + lane) * 1024 + (KT) + w * 8]);      \
    async16(&Als[B_][w][64][0], &Al[(size_t)(bm + 64 + lane) * 1024 + (KT) + w * 8]); \
    async16(&Bhs[B_][w][0][0],  &Bh[(size_t)(bnl + lane) * 1024 + (KT) + w * 8]);     \
    async16(&Bls[B_][w][0][0],  &Bl[(size_t)(bnl + lane) * 1024 + (KT) + w * 8]);     \
  }

  STAGE(0, 0);
  __syncthreads();

  const int fr = lane & 15;
  const int fg = lane >> 4;
  int cur = 0;

  for (int kt = 0; kt < 1024; kt += 32) {
    if (kt + 32 < 1024) STAGE(cur ^ 1, kt + 32);

    u16x8 a_h[4], a_l[4], b_h[2], b_l[2];
    #pragma unroll
    for (int mf = 0; mf < 4; ++mf) {
      const int row = wr * 64 + mf * 16 + fr;
      a_h[mf] = *(const u16x8*)&Ahs[cur][fg][row][0];
      a_l[mf] = *(const u16x8*)&Als[cur][fg][row][0];
    }
    #pragma unroll
    for (int nf = 0; nf < 2; ++nf) {
      const int col = wc * 32 + nf * 16 + fr;
      b_h[nf] = *(const u16x8*)&Bhs[cur][fg][col][0];
      b_l[nf] = *(const u16x8*)&Bls[cur][fg][col][0];
    }
    #pragma unroll
    for (int mf = 0; mf < 4; ++mf)
      #pragma unroll
      for (int nf = 0; nf < 2; ++nf) {
        acc[mf][nf] = __builtin_amdgcn_mfma_f32_16x16x32_bf16(a_h[mf], b_h[nf], acc[mf][nf], 0, 0, 0);
        acc[mf][nf] = __builtin_amdgcn_mfma_f32_16x16x32_bf16(a_h[mf], b_l[nf], acc[mf][nf], 0, 0, 0);
        acc[mf][nf] = __builtin_amdgcn_mfma_f32_16x16x32_bf16(a_l[mf], b_h[nf], acc[mf][nf], 0, 0, 0);
      }
    __syncthreads();
    cur ^= 1;
  }
#undef STAGE

  if (sel < 2) {
    const int c0 = bnl + wc * 32 + fr;
    const int c1 = c0 + 16;
    const float bb0 = bias[c0];
    const float bb1 = bias[c1];
    const int head = bnl >> 6;
    #pragma unroll
    for (int mf = 0; mf < 4; ++mf) {
      const int row0 = bm + wr * 64 + mf * 16;
      #pragma unroll
      for (int j = 0; j < 4; ++j) {
        const float v0 = acc[mf][0][j] + bb0;
        const float v1 = acc[mf][1][j] + bb1;
        const u64 b0 = __ballot(v0 > 1.0f);
        const u64 b1 = __ballot(v1 > 1.0f);
        const int m = row0 + fg * 4 + j;
        if (fr == 0) {
          const u32 mask = (u32)((b0 >> (fg * 16)) & 0xFFFFu)
                         | ((u32)((b1 >> (fg * 16)) & 0xFFFFu) << 16);
          pbits[(((size_t)sel * 4096 + m) * 16 + head) * 2 + wc] = mask;
        }
        if (__builtin_fabsf(v0 - 1.0f) < TAU) {
          const u32 s = atomicAdd(flagcnt, 1u);
          if (s < FCAP) flaglist[s] = ((u32)sel << 22) | ((u32)m << 10) | (u32)c0;
        }
        if (__builtin_fabsf(v1 - 1.0f) < TAU) {
          const u32 s = atomicAdd(flagcnt, 1u);
          if (s < FCAP) flaglist[s] = ((u32)sel << 22) | ((u32)m << 10) | (u32)c1;
        }
      }
    }
  } else {
    #pragma unroll
    for (int mf = 0; mf < 4; ++mf) {
      const int row0 = bm + wr * 64 + mf * 16 + fg * 4;
      #pragma unroll
      for (int nf = 0; nf < 2; ++nf) {
        const int col = bnl + wc * 32 + nf * 16 + fr;
        const float bb = bias[col];
        const int bb_ = row0 >> 11, t0 = row0 & 2047;
        const int hh = col >> 6, dd = col & 63;
        u16x4 o;
        o[0] = f2bf(acc[mf][nf][0] + bb);
        o[1] = f2bf(acc[mf][nf][1] + bb);
        o[2] = f2bf(acc[mf][nf][2] + bb);
        o[3] = f2bf(acc[mf][nf][3] + bb);
        *(u16x4*)&vT[(((size_t)(bb_ * 16 + hh)) * 64 + dd) * 2048 + t0] = o;
      }
    }
  }
}

// ---------------------------------------------------------------------------
// Recompute near-threshold q/k entries with exact fp32 dot; patch via
// atomicXor (verified).
// ---------------------------------------------------------------------------
__global__ __launch_bounds__(256) void fix_bits(
    const float* __restrict__ x,
    const float* __restrict__ Wq, const float* __restrict__ Wk,
    const float* __restrict__ bq, const float* __restrict__ bk,
    u32* __restrict__ pbits,
    const u32* __restrict__ flagcnt, const u32* __restrict__ flaglist)
{
  u32 cnt = *flagcnt;
  if (cnt > FCAP) cnt = FCAP;
  const int lane = threadIdx.x & 63;
  const u32 wid  = (blockIdx.x * 256 + threadIdx.x) >> 6;
  const u32 nw   = gridDim.x * 4;
  for (u32 i = wid; i < cnt; i += nw) {
    const u32 e = flaglist[i];
    const int which = e >> 22;
    const int m = (e >> 10) & 4095;
    const int n = e & 1023;
    const float* W    = which ? Wk : Wq;
    const float* bias = which ? bk : bq;
    float s = 0.f;
    #pragma unroll
    for (int j = 0; j < 16; ++j)
      s += x[(size_t)m * 1024 + lane + j * 64] * W[(size_t)n * 1024 + lane + j * 64];
    #pragma unroll
    for (int off = 32; off > 0; off >>= 1) s += __shfl_xor(s, off);
    const float val = s + bias[n];
    if (lane == 0) {
      const size_t idx = (((size_t)which * 4096 + m) * 16 + (n >> 6)) * 2 + ((n >> 5) & 1);
      const u32 bit = 1u << (n & 31);
      const bool oldb = (pbits[idx] >> (n & 31)) & 1u;
      const bool newb = val > 1.0f;
      if (oldb != newb) atomicXor(&pbits[idx], bit);
    }
  }
}

// ---------------------------------------------------------------------------
// MFMA attention (verified): per block = (bh, 64-query tile).
// ---------------------------------------------------------------------------
__global__ __launch_bounds__(256) void attn_mfma(
    const u32* __restrict__ pbits, const u16* __restrict__ vT,
    u16* __restrict__ oh, u16* __restrict__ ol)
{
  __shared__ u16 wtb[64][72];
  __shared__ u16 vtb[64][72];
  __shared__ u64 kbt[64];
  __shared__ float zred[256];
  __shared__ float zfin[64];

  const int tid = threadIdx.x, lane = tid & 63, w = tid >> 6;
  const int bid = blockIdx.x;
  const int qt = bid & 31, bh = bid >> 5, b = bh >> 4, h = bh & 15;

  const int qw = tid >> 2, ks0 = (tid & 3) << 4;
  const int qm = b * T_LEN + qt * 64 + qw;
  const size_t qbase = (((size_t)qm) * 16 + h) * 2;
  const u64 myqb = (u64)pbits[qbase] | ((u64)pbits[qbase + 1] << 32);
  float zacc = 0.f;

  f32x4 acc[4];
  #pragma unroll
  for (int nf = 0; nf < 4; ++nf) acc[nf] = (f32x4){0.f, 0.f, 0.f, 0.f};

  const u16* vbase = vT + (size_t)bh * 64 * T_LEN;
  const int sd = tid >> 2, sk = (tid & 3) << 3;
  const int fr = lane & 15, fg = lane >> 4;

  for (int kt = 0; kt < T_LEN; kt += 64) {
    *(u16x8*)&vtb[sd][sk]      = *(const u16x8*)&vbase[(size_t)sd * T_LEN + kt + sk];
    *(u16x8*)&vtb[sd][sk + 32] = *(const u16x8*)&vbase[(size_t)sd * T_LEN + kt + sk + 32];
    if (tid < 64) {
      const int km = b * T_LEN + kt + tid;
      const size_t kb = (((size_t)(4096 + km)) * 16 + h) * 2;
      kbt[tid] = (u64)pbits[kb] | ((u64)pbits[kb + 1] << 32);
    }
    __syncthreads();

    #pragma unroll
    for (int i = 0; i < 16; ++i) {
      const int kk = ks0 + i;
      const int mm = __popcll(myqb & kbt[kk]);
      const u16 wb = f2bf(__expf((float)mm * 0.125f));
      wtb[qw][kk] = wb;
      zacc += bf2f(wb);
    }
    __syncthreads();

    #pragma unroll
    for (int ks = 0; ks < 2; ++ks) {
      const u16x8 af = *(const u16x8*)&wtb[w * 16 + fr][ks * 32 + fg * 8];
      #pragma unroll
      for (int nf = 0; nf < 4; ++nf) {
        const u16x8 bfv = *(const u16x8*)&vtb[nf * 16 + fr][ks * 32 + fg * 8];
        acc[nf] = __builtin_amdgcn_mfma_f32_16x16x32_bf16(af, bfv, acc[nf], 0, 0, 0);
      }
    }
    __syncthreads();
  }

  zred[tid] = zacc;
  __syncthreads();
  if (tid < 64)
    zfin[tid] = zred[tid * 4] + zred[tid * 4 + 1] + zred[tid * 4 + 2] + zred[tid * 4 + 3];
  __syncthreads();

  #pragma unroll
  for (int nf = 0; nf < 4; ++nf) {
    const int col = h * 64 + nf * 16 + fr;
    #pragma unroll
    for (int j = 0; j < 4; ++j) {
      const int qrow = w * 16 + fg * 4 + j;
      const float o = acc[nf][j] / zfin[qrow];
      const size_t gq = (size_t)b * T_LEN + qt * 64 + qrow;
      const u16 hb = f2bf(o);
      oh[gq * 1024 + col] = hb;
      ol[gq * 1024 + col] = f2bf(o - bf2f(hb));
    }
  }
}

// ---------------------------------------------------------------------------
// Out projection: 3-pass split-bf16 MFMA, fp32 out + bias; same T3 staging.
// ---------------------------------------------------------------------------
__global__ __launch_bounds__(256) void mfma_out(
    const u16* __restrict__ Ah, const u16* __restrict__ Al,
    const u16* __restrict__ Bh, const u16* __restrict__ Bl,
    const float* __restrict__ bias, float* __restrict__ out)
{
  __shared__ u16 Ahs[2][4][128][8];
  __shared__ u16 Als[2][4][128][8];
  __shared__ u16 Bhs[2][4][64][8];
  __shared__ u16 Bls[2][4][64][8];

  const int tid  = threadIdx.x;
  const int lane = tid & 63;
  const int w    = tid >> 6;
  const int wr   = w & 1;
  const int wc   = w >> 1;
  const int bm   = blockIdx.x * 128;
  const int bn   = blockIdx.y * 64;

  f32x4 acc[4][2];
  #pragma unroll
  for (int mf = 0; mf < 4; ++mf)
    #pragma unroll
    for (int nf = 0; nf < 2; ++nf) acc[mf][nf] = (f32x4){0.f, 0.f, 0.f, 0.f};

#define STAGE(B_, KT)                                                          \
  {                                                                            \
    async16(&Ahs[B_][w][0][0],  &Ah[(size_t)(bm + lane) * 1024 + (KT) + w * 8]);      \
    async16(&Ahs[B_][w][64][0], &Ah[(size_t)(bm + 64 + lane) * 1024 + (KT) + w * 8]); \
    async16(&Als[B_][w][0][0],  &Al[(size_t)(bm + lane) * 1024 + (KT) + w * 8]);      \
    async16(&Als[B_][w][64][0], &Al[(size_t)(bm + 64 + lane) * 1024 + (KT) + w * 8]); \
    async16(&Bhs[B_][w][0][0],  &Bh[(size_t)(bn + lane) * 1024 + (KT) + w * 8]);      \
    async16(&Bls[B_][w][0][0],  &Bl[(size_t)(bn + lane) * 1024 + (KT) + w * 8]);      \
  }

  STAGE(0, 0);
  __syncthreads();

  const int fr = lane & 15;
  const int fg = lane >> 4;
  int cur = 0;

  for (int kt = 0; kt < 1024; kt += 32) {
    if (kt + 32 < 1024) STAGE(cur ^ 1, kt + 32);

    u16x8 a_h[4], a_l[4], b_h[2], b_l[2];
    #pragma unroll
    for (int mf = 0; mf < 4; ++mf) {
      const int row = wr * 64 + mf * 16 + fr;
      a_h[mf] = *(const u16x8*)&Ahs[cur][fg][row][0];
      a_l[mf] = *(const u16x8*)&Als[cur][fg][row][0];
    }
    #pragma unroll
    for (int nf = 0; nf < 2; ++nf) {
      const int col = wc * 32 + nf * 16 + fr;
      b_h[nf] = *(const u16x8*)&Bhs[cur][fg][col][0];
      b_l[nf] = *(const u16x8*)&Bls[cur][fg][col][0];
    }
    #pragma unroll
    for (int mf = 0; mf < 4; ++mf)
      #pragma unroll
      for (int nf = 0; nf < 2; ++nf) {
        acc[mf][nf] = __builtin_amdgcn_mfma_f32_16x16x32_bf16(a_h[mf], b_h[nf], acc[mf][nf], 0, 0, 0);
        acc[mf][nf] = __builtin_amdgcn_mfma_f32_16x16x32_bf16(a_h[mf], b_l[nf], acc[mf][nf], 0, 0, 0);
        acc[mf][nf] = __builtin_amdgcn_mfma_f32_16x16x32_bf16(a_l[mf], b_h[nf], acc[mf][nf], 0, 0, 0);
      }
    __syncthreads();
    cur ^= 1;
  }
#undef STAGE

  #pragma unroll
  for (int mf = 0; mf < 4; ++mf) {
    const int row0 = bm + wr * 64 + mf * 16 + fg * 4;
    #pragma unroll
    for (int nf = 0; nf < 2; ++nf) {
      const int col = bn + wc * 32 + nf * 16 + fr;
      const float bb = bias[col];
      #pragma unroll
      for (int j = 0; j < 4; ++j)
        out[(size_t)(row0 + j) * 1024 + col] = acc[mf][nf][j] + bb;
    }
  }
}

// ---------------------------------------------------------------------------
extern "C" void kernel_launch(void* const* d_in, const int* in_sizes, int n_in,
                              void* d_out, int out_size, void* d_ws, size_t ws_size,
                              hipStream_t stream) {
  const float* x  = (const float*)d_in[0];
  const float* Wq = (const float*)d_in[1];
  const float* bq = (const float*)d_in[2];
  const float* Wk = (const float*)d_in[3];
  const float* bk = (const float*)d_in[4];
  const float* Wv = (const float*)d_in[5];
  const float* bv = (const float*)d_in[6];
  const float* Wo = (const float*)d_in[7];
  const float* bo = (const float*)d_in[8];
  float* out = (float*)d_out;

  char* ws = (char*)d_ws;
  u16* oh   = (u16*)ws;
  u16* ol   = (u16*)(ws + 8 * MB);
  u16* xh   = (u16*)(ws + 16 * MB);
  u16* xl   = (u16*)(ws + 24 * MB);
  u16* vT   = (u16*)(ws + 32 * MB);
  u16* Woh  = (u16*)(ws + 40 * MB);
  u16* Wol  = (u16*)(ws + 42 * MB);
  u32* pbits = (u32*)(ws + 44 * MB);
  u32* flagcnt  = (u32*)(ws + 45 * MB);
  u32* flaglist = (u32*)(ws + 45 * MB + 256);

  // d_out doubles as scratch for q/k/v weight splits (dead before out-proj).
  char* dob = (char*)d_out;
  u16* Wqh = (u16*)dob;
  u16* Wql = (u16*)(dob + 2 * MB);
  u16* Wkh = (u16*)(dob + 4 * MB);
  u16* Wkl = (u16*)(dob + 6 * MB);
  u16* Wvh = (u16*)(dob + 8 * MB);
  u16* Wvl = (u16*)(dob + 10 * MB);

  split_all<<<8192, 256, 0, stream>>>(x, Wq, Wk, Wv, Wo,
                                      xh, xl, Wqh, Wql, Wkh, Wkl,
                                      Wvh, Wvl, Woh, Wol, flagcnt);

  dim3 g1(M_ROWS / 128, 3072 / 64);
  mfma_qkv<<<g1, 256, 0, stream>>>(xh, xl, Wqh, Wql, Wkh, Wkl, Wvh, Wvl,
                                   bq, bk, bv, pbits, flagcnt, flaglist, vT);

  fix_bits<<<64, 256, 0, stream>>>(x, Wq, Wk, bq, bk, pbits, flagcnt, flaglist);

  attn_mfma<<<32 * 32, 256, 0, stream>>>(pbits, vT, oh, ol);

  dim3 g2(M_ROWS / 128, 1024 / 64);
  mfma_out<<<g2, 256, 0, stream>>>(oh, ol, Woh, Wol, bo, out);
}

// Round 5
// 225.222 us; speedup vs baseline: 1.3251x; 1.3251x over previous
//
#include <hip/hip_runtime.h>
#include <cstdint>

typedef unsigned long long u64;
typedef unsigned int u32;
typedef unsigned short u16;
typedef __attribute__((ext_vector_type(8))) u16 u16x8;
typedef __attribute__((ext_vector_type(4))) u16 u16x4;
typedef __attribute__((ext_vector_type(4))) float f32x4;

#define T_LEN 2048
#define C_DIM 1024
#define H_NUM 16
#define M_ROWS 4096  // B*T
#define MB (1024ull * 1024ull)
#define TAU 2e-4f
#define FCAP 65536u

// bf16 helpers (manual RNE, finite inputs only)
__device__ __forceinline__ u16 f2bf(float f) {
  unsigned u = __builtin_bit_cast(unsigned, f);
  return (u16)((u + 0x7FFFu + ((u >> 16) & 1u)) >> 16);
}
__device__ __forceinline__ float bf2f(u16 u) {
  return __builtin_bit_cast(float, ((unsigned)u) << 16);
}

// async global->LDS, 16B/lane: LDS dest = wave-uniform base + lane*16,
// global src = per-lane pointer.
__device__ __forceinline__ void async16(u16* lds, const u16* g) {
  __builtin_amdgcn_global_load_lds(
      (const __attribute__((address_space(1))) void*)g,
      (__attribute__((address_space(3))) void*)lds, 16, 0, 0);
}

// ---------------------------------------------------------------------------
// Split fp32 -> (hi,lo) bf16 for x, Wq, Wk, Wv, Wo in one launch.
// ---------------------------------------------------------------------------
__global__ __launch_bounds__(256) void split_all(
    const float* __restrict__ x,  const float* __restrict__ Wq,
    const float* __restrict__ Wk, const float* __restrict__ Wv,
    const float* __restrict__ Wo,
    u16* xh, u16* xl, u16* wqh, u16* wql, u16* wkh, u16* wkl,
    u16* wvh, u16* wvl, u16* woh, u16* wol, u32* flagcnt)
{
  const int i = blockIdx.x * 256 + threadIdx.x;
  if (i == 0) *flagcnt = 0;
  const float* src; u16 *hi, *lo; int off;
  if      (i < 1048576) { src = x;  hi = xh;  lo = xl;  off = i; }
  else if (i < 1310720) { src = Wq; hi = wqh; lo = wql; off = i - 1048576; }
  else if (i < 1572864) { src = Wk; hi = wkh; lo = wkl; off = i - 1310720; }
  else if (i < 1835008) { src = Wv; hi = wvh; lo = wvl; off = i - 1572864; }
  else                  { src = Wo; hi = woh; lo = wol; off = i - 1835008; }
  const float4 v = ((const float4*)src)[off];
  u16x4 h, l;
  float t;
  t = v.x; h[0] = f2bf(t); l[0] = f2bf(t - bf2f(h[0]));
  t = v.y; h[1] = f2bf(t); l[1] = f2bf(t - bf2f(h[1]));
  t = v.z; h[2] = f2bf(t); l[2] = f2bf(t - bf2f(h[2]));
  t = v.w; h[3] = f2bf(t); l[3] = f2bf(t - bf2f(h[3]));
  ((u16x4*)hi)[off] = h;
  ((u16x4*)lo)[off] = l;
}

// ---------------------------------------------------------------------------
// Fused QKV 3-pass split-bf16 MFMA GEMM over N=3072 (sel 0:q, 1:k, 2:v).
// BM=128, BN=64, BK=32, 4 waves. global_load_lds staging into row-major
// double-buffered LDS [row][32] with T2 XOR swizzle (col16 ^= (row>>1)&3)
// applied on the GLOBAL SOURCE (rule #21: gload_lds dest is linear) and the
// SAME XOR on the ds_read address. Coalescing: 4 lanes = one 64B row chunk.
// Read banks: 2-way (free). Epilogues as round 3 (verified).
// ---------------------------------------------------------------------------
__global__ __launch_bounds__(256) void mfma_qkv(
    const u16* __restrict__ Ah, const u16* __restrict__ Al,
    const u16* __restrict__ Bqh, const u16* __restrict__ Bql,
    const u16* __restrict__ Bkh, const u16* __restrict__ Bkl,
    const u16* __restrict__ Bvh, const u16* __restrict__ Bvl,
    const float* __restrict__ bq, const float* __restrict__ bk,
    const float* __restrict__ bv,
    u32* __restrict__ pbits, u32* __restrict__ flagcnt,
    u32* __restrict__ flaglist, u16* __restrict__ vT)
{
  __shared__ u16 Ahs[2][128][32];   // 16 KB
  __shared__ u16 Als[2][128][32];   // 16 KB
  __shared__ u16 Bhs[2][64][32];    //  8 KB
  __shared__ u16 Bls[2][64][32];    //  8 KB

  const int tid  = threadIdx.x;
  const int lane = tid & 63;
  const int w    = tid >> 6;
  const int wr   = w & 1;
  const int wc   = w >> 1;
  const int bm   = blockIdx.x * 128;
  const int bng  = blockIdx.y * 64;
  const int sel  = bng >> 10;
  const int bnl  = bng & 1023;

  const u16* Bh   = (sel == 0) ? Bqh : (sel == 1) ? Bkh : Bvh;
  const u16* Bl   = (sel == 0) ? Bql : (sel == 1) ? Bkl : Bvl;
  const float* bias = (sel == 0) ? bq : (sel == 1) ? bk : bv;

  f32x4 acc[4][2];
  #pragma unroll
  for (int mf = 0; mf < 4; ++mf)
    #pragma unroll
    for (int nf = 0; nf < 2; ++nf) acc[mf][nf] = (f32x4){0.f, 0.f, 0.f, 0.f};

  const int sr = lane >> 2;   // row within 16-row chunk
  const int sc = lane & 3;    // 16B slot within 64B row

  // One instruction stages 16 rows x 64B. Physical slot (r, sc) holds
  // logical col16 = sc ^ ((r>>1)&3)  (inverse-swizzled source).
#define STG(DST, SRC, TB, R0, KT)                                          \
  async16(&DST[(R0)][0],                                                   \
          &SRC[(size_t)((TB) + (R0) + sr) * 1024 + (KT) +                  \
               ((sc ^ ((((R0) + sr) >> 1) & 3)) << 3)]);

#define STAGE(B_, KT)                        \
  {                                          \
    STG(Ahs[B_], Ah, bm, w * 32, KT);        \
    STG(Ahs[B_], Ah, bm, w * 32 + 16, KT);   \
    STG(Als[B_], Al, bm, w * 32, KT);        \
    STG(Als[B_], Al, bm, w * 32 + 16, KT);   \
    STG(Bhs[B_], Bh, bnl, w * 16, KT);       \
    STG(Bls[B_], Bl, bnl, w * 16, KT);       \
  }

  STAGE(0, 0);
  __syncthreads();

  const int fr = lane & 15;
  const int fg = lane >> 4;
  int cur = 0;

  for (int kt = 0; kt < 1024; kt += 32) {
    if (kt + 32 < 1024) STAGE(cur ^ 1, kt + 32);

    u16x8 a_h[4], a_l[4], b_h[2], b_l[2];
    #pragma unroll
    for (int mf = 0; mf < 4; ++mf) {
      const int row = wr * 64 + mf * 16 + fr;
      const int cs = (fg ^ ((row >> 1) & 3)) << 3;
      a_h[mf] = *(const u16x8*)&Ahs[cur][row][cs];
      a_l[mf] = *(const u16x8*)&Als[cur][row][cs];
    }
    #pragma unroll
    for (int nf = 0; nf < 2; ++nf) {
      const int col = wc * 32 + nf * 16 + fr;
      const int cs = (fg ^ ((col >> 1) & 3)) << 3;
      b_h[nf] = *(const u16x8*)&Bhs[cur][col][cs];
      b_l[nf] = *(const u16x8*)&Bls[cur][col][cs];
    }
    #pragma unroll
    for (int mf = 0; mf < 4; ++mf)
      #pragma unroll
      for (int nf = 0; nf < 2; ++nf) {
        acc[mf][nf] = __builtin_amdgcn_mfma_f32_16x16x32_bf16(a_h[mf], b_h[nf], acc[mf][nf], 0, 0, 0);
        acc[mf][nf] = __builtin_amdgcn_mfma_f32_16x16x32_bf16(a_h[mf], b_l[nf], acc[mf][nf], 0, 0, 0);
        acc[mf][nf] = __builtin_amdgcn_mfma_f32_16x16x32_bf16(a_l[mf], b_h[nf], acc[mf][nf], 0, 0, 0);
      }
    __syncthreads();
    cur ^= 1;
  }
#undef STAGE
#undef STG

  if (sel < 2) {
    const int c0 = bnl + wc * 32 + fr;
    const int c1 = c0 + 16;
    const float bb0 = bias[c0];
    const float bb1 = bias[c1];
    const int head = bnl >> 6;
    #pragma unroll
    for (int mf = 0; mf < 4; ++mf) {
      const int row0 = bm + wr * 64 + mf * 16;
      #pragma unroll
      for (int j = 0; j < 4; ++j) {
        const float v0 = acc[mf][0][j] + bb0;
        const float v1 = acc[mf][1][j] + bb1;
        const u64 b0 = __ballot(v0 > 1.0f);
        const u64 b1 = __ballot(v1 > 1.0f);
        const int m = row0 + fg * 4 + j;
        if (fr == 0) {
          const u32 mask = (u32)((b0 >> (fg * 16)) & 0xFFFFu)
                         | ((u32)((b1 >> (fg * 16)) & 0xFFFFu) << 16);
          pbits[(((size_t)sel * 4096 + m) * 16 + head) * 2 + wc] = mask;
        }
        if (__builtin_fabsf(v0 - 1.0f) < TAU) {
          const u32 s = atomicAdd(flagcnt, 1u);
          if (s < FCAP) flaglist[s] = ((u32)sel << 22) | ((u32)m << 10) | (u32)c0;
        }
        if (__builtin_fabsf(v1 - 1.0f) < TAU) {
          const u32 s = atomicAdd(flagcnt, 1u);
          if (s < FCAP) flaglist[s] = ((u32)sel << 22) | ((u32)m << 10) | (u32)c1;
        }
      }
    }
  } else {
    #pragma unroll
    for (int mf = 0; mf < 4; ++mf) {
      const int row0 = bm + wr * 64 + mf * 16 + fg * 4;
      #pragma unroll
      for (int nf = 0; nf < 2; ++nf) {
        const int col = bnl + wc * 32 + nf * 16 + fr;
        const float bb = bias[col];
        const int bb_ = row0 >> 11, t0 = row0 & 2047;
        const int hh = col >> 6, dd = col & 63;
        u16x4 o;
        o[0] = f2bf(acc[mf][nf][0] + bb);
        o[1] = f2bf(acc[mf][nf][1] + bb);
        o[2] = f2bf(acc[mf][nf][2] + bb);
        o[3] = f2bf(acc[mf][nf][3] + bb);
        *(u16x4*)&vT[(((size_t)(bb_ * 16 + hh)) * 64 + dd) * 2048 + t0] = o;
      }
    }
  }
}

// ---------------------------------------------------------------------------
// Recompute near-threshold q/k entries with exact fp32 dot; patch via
// atomicXor (verified).
// ---------------------------------------------------------------------------
__global__ __launch_bounds__(256) void fix_bits(
    const float* __restrict__ x,
    const float* __restrict__ Wq, const float* __restrict__ Wk,
    const float* __restrict__ bq, const float* __restrict__ bk,
    u32* __restrict__ pbits,
    const u32* __restrict__ flagcnt, const u32* __restrict__ flaglist)
{
  u32 cnt = *flagcnt;
  if (cnt > FCAP) cnt = FCAP;
  const int lane = threadIdx.x & 63;
  const u32 wid  = (blockIdx.x * 256 + threadIdx.x) >> 6;
  const u32 nw   = gridDim.x * 4;
  for (u32 i = wid; i < cnt; i += nw) {
    const u32 e = flaglist[i];
    const int which = e >> 22;
    const int m = (e >> 10) & 4095;
    const int n = e & 1023;
    const float* W    = which ? Wk : Wq;
    const float* bias = which ? bk : bq;
    float s = 0.f;
    #pragma unroll
    for (int j = 0; j < 16; ++j)
      s += x[(size_t)m * 1024 + lane + j * 64] * W[(size_t)n * 1024 + lane + j * 64];
    #pragma unroll
    for (int off = 32; off > 0; off >>= 1) s += __shfl_xor(s, off);
    const float val = s + bias[n];
    if (lane == 0) {
      const size_t idx = (((size_t)which * 4096 + m) * 16 + (n >> 6)) * 2 + ((n >> 5) & 1);
      const u32 bit = 1u << (n & 31);
      const bool oldb = (pbits[idx] >> (n & 31)) & 1u;
      const bool newb = val > 1.0f;
      if (oldb != newb) atomicXor(&pbits[idx], bit);
    }
  }
}

// ---------------------------------------------------------------------------
// MFMA attention (verified): per block = (bh, 64-query tile).
// ---------------------------------------------------------------------------
__global__ __launch_bounds__(256) void attn_mfma(
    const u32* __restrict__ pbits, const u16* __restrict__ vT,
    u16* __restrict__ oh, u16* __restrict__ ol)
{
  __shared__ u16 wtb[64][72];
  __shared__ u16 vtb[64][72];
  __shared__ u64 kbt[64];
  __shared__ float zred[256];
  __shared__ float zfin[64];

  const int tid = threadIdx.x, lane = tid & 63, w = tid >> 6;
  const int bid = blockIdx.x;
  const int qt = bid & 31, bh = bid >> 5, b = bh >> 4, h = bh & 15;

  const int qw = tid >> 2, ks0 = (tid & 3) << 4;
  const int qm = b * T_LEN + qt * 64 + qw;
  const size_t qbase = (((size_t)qm) * 16 + h) * 2;
  const u64 myqb = (u64)pbits[qbase] | ((u64)pbits[qbase + 1] << 32);
  float zacc = 0.f;

  f32x4 acc[4];
  #pragma unroll
  for (int nf = 0; nf < 4; ++nf) acc[nf] = (f32x4){0.f, 0.f, 0.f, 0.f};

  const u16* vbase = vT + (size_t)bh * 64 * T_LEN;
  const int sd = tid >> 2, sk = (tid & 3) << 3;
  const int fr = lane & 15, fg = lane >> 4;

  for (int kt = 0; kt < T_LEN; kt += 64) {
    *(u16x8*)&vtb[sd][sk]      = *(const u16x8*)&vbase[(size_t)sd * T_LEN + kt + sk];
    *(u16x8*)&vtb[sd][sk + 32] = *(const u16x8*)&vbase[(size_t)sd * T_LEN + kt + sk + 32];
    if (tid < 64) {
      const int km = b * T_LEN + kt + tid;
      const size_t kb = (((size_t)(4096 + km)) * 16 + h) * 2;
      kbt[tid] = (u64)pbits[kb] | ((u64)pbits[kb + 1] << 32);
    }
    __syncthreads();

    #pragma unroll
    for (int i = 0; i < 16; ++i) {
      const int kk = ks0 + i;
      const int mm = __popcll(myqb & kbt[kk]);
      const u16 wb = f2bf(__expf((float)mm * 0.125f));
      wtb[qw][kk] = wb;
      zacc += bf2f(wb);
    }
    __syncthreads();

    #pragma unroll
    for (int ks = 0; ks < 2; ++ks) {
      const u16x8 af = *(const u16x8*)&wtb[w * 16 + fr][ks * 32 + fg * 8];
      #pragma unroll
      for (int nf = 0; nf < 4; ++nf) {
        const u16x8 bfv = *(const u16x8*)&vtb[nf * 16 + fr][ks * 32 + fg * 8];
        acc[nf] = __builtin_amdgcn_mfma_f32_16x16x32_bf16(af, bfv, acc[nf], 0, 0, 0);
      }
    }
    __syncthreads();
  }

  zred[tid] = zacc;
  __syncthreads();
  if (tid < 64)
    zfin[tid] = zred[tid * 4] + zred[tid * 4 + 1] + zred[tid * 4 + 2] + zred[tid * 4 + 3];
  __syncthreads();

  #pragma unroll
  for (int nf = 0; nf < 4; ++nf) {
    const int col = h * 64 + nf * 16 + fr;
    #pragma unroll
    for (int j = 0; j < 4; ++j) {
      const int qrow = w * 16 + fg * 4 + j;
      const float o = acc[nf][j] / zfin[qrow];
      const size_t gq = (size_t)b * T_LEN + qt * 64 + qrow;
      const u16 hb = f2bf(o);
      oh[gq * 1024 + col] = hb;
      ol[gq * 1024 + col] = f2bf(o - bf2f(hb));
    }
  }
}

// ---------------------------------------------------------------------------
// Out projection: 3-pass split-bf16 MFMA, fp32 out + bias; same swizzled
// gload_lds staging as mfma_qkv.
// ---------------------------------------------------------------------------
__global__ __launch_bounds__(256) void mfma_out(
    const u16* __restrict__ Ah, const u16* __restrict__ Al,
    const u16* __restrict__ Bh, const u16* __restrict__ Bl,
    const float* __restrict__ bias, float* __restrict__ out)
{
  __shared__ u16 Ahs[2][128][32];
  __shared__ u16 Als[2][128][32];
  __shared__ u16 Bhs[2][64][32];
  __shared__ u16 Bls[2][64][32];

  const int tid  = threadIdx.x;
  const int lane = tid & 63;
  const int w    = tid >> 6;
  const int wr   = w & 1;
  const int wc   = w >> 1;
  const int bm   = blockIdx.x * 128;
  const int bn   = blockIdx.y * 64;

  f32x4 acc[4][2];
  #pragma unroll
  for (int mf = 0; mf < 4; ++mf)
    #pragma unroll
    for (int nf = 0; nf < 2; ++nf) acc[mf][nf] = (f32x4){0.f, 0.f, 0.f, 0.f};

  const int sr = lane >> 2;
  const int sc = lane & 3;

#define STG(DST, SRC, TB, R0, KT)                                          \
  async16(&DST[(R0)][0],                                                   \
          &SRC[(size_t)((TB) + (R0) + sr) * 1024 + (KT) +                  \
               ((sc ^ ((((R0) + sr) >> 1) & 3)) << 3)]);

#define STAGE(B_, KT)                        \
  {                                          \
    STG(Ahs[B_], Ah, bm, w * 32, KT);        \
    STG(Ahs[B_], Ah, bm, w * 32 + 16, KT);   \
    STG(Als[B_], Al, bm, w * 32, KT);        \
    STG(Als[B_], Al, bm, w * 32 + 16, KT);   \
    STG(Bhs[B_], Bh, bn, w * 16, KT);        \
    STG(Bls[B_], Bl, bn, w * 16, KT);        \
  }

  STAGE(0, 0);
  __syncthreads();

  const int fr = lane & 15;
  const int fg = lane >> 4;
  int cur = 0;

  for (int kt = 0; kt < 1024; kt += 32) {
    if (kt + 32 < 1024) STAGE(cur ^ 1, kt + 32);

    u16x8 a_h[4], a_l[4], b_h[2], b_l[2];
    #pragma unroll
    for (int mf = 0; mf < 4; ++mf) {
      const int row = wr * 64 + mf * 16 + fr;
      const int cs = (fg ^ ((row >> 1) & 3)) << 3;
      a_h[mf] = *(const u16x8*)&Ahs[cur][row][cs];
      a_l[mf] = *(const u16x8*)&Als[cur][row][cs];
    }
    #pragma unroll
    for (int nf = 0; nf < 2; ++nf) {
      const int col = wc * 32 + nf * 16 + fr;
      const int cs = (fg ^ ((col >> 1) & 3)) << 3;
      b_h[nf] = *(const u16x8*)&Bhs[cur][col][cs];
      b_l[nf] = *(const u16x8*)&Bls[cur][col][cs];
    }
    #pragma unroll
    for (int mf = 0; mf < 4; ++mf)
      #pragma unroll
      for (int nf = 0; nf < 2; ++nf) {
        acc[mf][nf] = __builtin_amdgcn_mfma_f32_16x16x32_bf16(a_h[mf], b_h[nf], acc[mf][nf], 0, 0, 0);
        acc[mf][nf] = __builtin_amdgcn_mfma_f32_16x16x32_bf16(a_h[mf], b_l[nf], acc[mf][nf], 0, 0, 0);
        acc[mf][nf] = __builtin_amdgcn_mfma_f32_16x16x32_bf16(a_l[mf], b_h[nf], acc[mf][nf], 0, 0, 0);
      }
    __syncthreads();
    cur ^= 1;
  }
#undef STAGE
#undef STG

  #pragma unroll
  for (int mf = 0; mf < 4; ++mf) {
    const int row0 = bm + wr * 64 + mf * 16 + fg * 4;
    #pragma unroll
    for (int nf = 0; nf < 2; ++nf) {
      const int col = bn + wc * 32 + nf * 16 + fr;
      const float bb = bias[col];
      #pragma unroll
      for (int j = 0; j < 4; ++j)
        out[(size_t)(row0 + j) * 1024 + col] = acc[mf][nf][j] + bb;
    }
  }
}

// ---------------------------------------------------------------------------
extern "C" void kernel_launch(void* const* d_in, const int* in_sizes, int n_in,
                              void* d_out, int out_size, void* d_ws, size_t ws_size,
                              hipStream_t stream) {
  const float* x  = (const float*)d_in[0];
  const float* Wq = (const float*)d_in[1];
  const float* bq = (const float*)d_in[2];
  const float* Wk = (const float*)d_in[3];
  const float* bk = (const float*)d_in[4];
  const float* Wv = (const float*)d_in[5];
  const float* bv = (const float*)d_in[6];
  const float* Wo = (const float*)d_in[7];
  const float* bo = (const float*)d_in[8];
  float* out = (float*)d_out;

  char* ws = (char*)d_ws;
  u16* oh   = (u16*)ws;
  u16* ol   = (u16*)(ws + 8 * MB);
  u16* xh   = (u16*)(ws + 16 * MB);
  u16* xl   = (u16*)(ws + 24 * MB);
  u16* vT   = (u16*)(ws + 32 * MB);
  u16* Woh  = (u16*)(ws + 40 * MB);
  u16* Wol  = (u16*)(ws + 42 * MB);
  u32* pbits = (u32*)(ws + 44 * MB);
  u32* flagcnt  = (u32*)(ws + 45 * MB);
  u32* flaglist = (u32*)(ws + 45 * MB + 256);

  // d_out doubles as scratch for q/k/v weight splits (dead before out-proj).
  char* dob = (char*)d_out;
  u16* Wqh = (u16*)dob;
  u16* Wql = (u16*)(dob + 2 * MB);
  u16* Wkh = (u16*)(dob + 4 * MB);
  u16* Wkl = (u16*)(dob + 6 * MB);
  u16* Wvh = (u16*)(dob + 8 * MB);
  u16* Wvl = (u16*)(dob + 10 * MB);

  split_all<<<8192, 256, 0, stream>>>(x, Wq, Wk, Wv, Wo,
                                      xh, xl, Wqh, Wql, Wkh, Wkl,
                                      Wvh, Wvl, Woh, Wol, flagcnt);

  dim3 g1(M_ROWS / 128, 3072 / 64);
  mfma_qkv<<<g1, 256, 0, stream>>>(xh, xl, Wqh, Wql, Wkh, Wkl, Wvh, Wvl,
                                   bq, bk, bv, pbits, flagcnt, flaglist, vT);

  fix_bits<<<64, 256, 0, stream>>>(x, Wq, Wk, bq, bk, pbits, flagcnt, flaglist);

  attn_mfma<<<32 * 32, 256, 0, stream>>>(pbits, vT, oh, ol);

  dim3 g2(M_ROWS / 128, 1024 / 64);
  mfma_out<<<g2, 256, 0, stream>>>(oh, ol, Woh, Wol, bo, out);
}

// Round 6
// 202.876 us; speedup vs baseline: 1.4711x; 1.1101x over previous
//
#include <hip/hip_runtime.h>
#include <cstdint>

typedef unsigned long long u64;
typedef unsigned int u32;
typedef unsigned short u16;
typedef __attribute__((ext_vector_type(8))) u16 u16x8;
typedef __attribute__((ext_vector_type(4))) u16 u16x4;
typedef __attribute__((ext_vector_type(4))) float f32x4;

#define T_LEN 2048
#define C_DIM 1024
#define H_NUM 16
#define M_ROWS 4096  // B*T
#define MB (1024ull * 1024ull)
#define TAU 2e-4f
#define FCAP 65536u

// bf16 helpers (manual RNE, finite inputs only)
__device__ __forceinline__ u16 f2bf(float f) {
  unsigned u = __builtin_bit_cast(unsigned, f);
  return (u16)((u + 0x7FFFu + ((u >> 16) & 1u)) >> 16);
}
__device__ __forceinline__ float bf2f(u16 u) {
  return __builtin_bit_cast(float, ((unsigned)u) << 16);
}

// async global->LDS, 16B/lane: LDS dest = wave-uniform base + lane*16,
// global src = per-lane pointer.
__device__ __forceinline__ void async16(u16* lds, const u16* g) {
  __builtin_amdgcn_global_load_lds(
      (const __attribute__((address_space(1))) void*)g,
      (__attribute__((address_space(3))) void*)lds, 16, 0, 0);
}

// ---------------------------------------------------------------------------
// Split fp32 -> (hi,lo) bf16 for x, Wq, Wk, Wv, Wo in one launch.
// (Wv/Wo lo halves are written but unused since round 6 — cost ~1 µs, kept
// for simplicity.)
// ---------------------------------------------------------------------------
__global__ __launch_bounds__(256) void split_all(
    const float* __restrict__ x,  const float* __restrict__ Wq,
    const float* __restrict__ Wk, const float* __restrict__ Wv,
    const float* __restrict__ Wo,
    u16* xh, u16* xl, u16* wqh, u16* wql, u16* wkh, u16* wkl,
    u16* wvh, u16* wvl, u16* woh, u16* wol, u32* flagcnt)
{
  const int i = blockIdx.x * 256 + threadIdx.x;
  if (i == 0) *flagcnt = 0;
  const float* src; u16 *hi, *lo; int off;
  if      (i < 1048576) { src = x;  hi = xh;  lo = xl;  off = i; }
  else if (i < 1310720) { src = Wq; hi = wqh; lo = wql; off = i - 1048576; }
  else if (i < 1572864) { src = Wk; hi = wkh; lo = wkl; off = i - 1310720; }
  else if (i < 1835008) { src = Wv; hi = wvh; lo = wvl; off = i - 1572864; }
  else                  { src = Wo; hi = woh; lo = wol; off = i - 1835008; }
  const float4 v = ((const float4*)src)[off];
  u16x4 h, l;
  float t;
  t = v.x; h[0] = f2bf(t); l[0] = f2bf(t - bf2f(h[0]));
  t = v.y; h[1] = f2bf(t); l[1] = f2bf(t - bf2f(h[1]));
  t = v.z; h[2] = f2bf(t); l[2] = f2bf(t - bf2f(h[2]));
  t = v.w; h[3] = f2bf(t); l[3] = f2bf(t - bf2f(h[3]));
  ((u16x4*)hi)[off] = h;
  ((u16x4*)lo)[off] = l;
}

// ---------------------------------------------------------------------------
// Fused QKV MFMA GEMM over N=3072 (sel 0:q, 1:k, 2:v).
// q/k: 3-pass split-bf16 (spike accuracy, feeds fix_bits tau=2e-4 band).
// v:   single-pass bf16 (error << bf16 storage rounding after softmax mean).
// BM=128, BN=64, BK=32, 4 waves. gload_lds staging, row-major LDS [row][32],
// T2 XOR swizzle on global source + ds_read (verified round 5).
// ---------------------------------------------------------------------------
__global__ __launch_bounds__(256) void mfma_qkv(
    const u16* __restrict__ Ah, const u16* __restrict__ Al,
    const u16* __restrict__ Bqh, const u16* __restrict__ Bql,
    const u16* __restrict__ Bkh, const u16* __restrict__ Bkl,
    const u16* __restrict__ Bvh,
    const float* __restrict__ bq, const float* __restrict__ bk,
    const float* __restrict__ bv,
    u32* __restrict__ pbits, u32* __restrict__ flagcnt,
    u32* __restrict__ flaglist, u16* __restrict__ vT)
{
  __shared__ u16 Ahs[2][128][32];   // 16 KB
  __shared__ u16 Als[2][128][32];   // 16 KB
  __shared__ u16 Bhs[2][64][32];    //  8 KB
  __shared__ u16 Bls[2][64][32];    //  8 KB

  const int tid  = threadIdx.x;
  const int lane = tid & 63;
  const int w    = tid >> 6;
  const int wr   = w & 1;
  const int wc   = w >> 1;
  const int bm   = blockIdx.x * 128;
  const int bng  = blockIdx.y * 64;
  const int sel  = bng >> 10;
  const int bnl  = bng & 1023;

  const u16* Bh   = (sel == 0) ? Bqh : (sel == 1) ? Bkh : Bvh;
  const u16* Bl   = (sel == 0) ? Bql : Bkl;   // unused when sel==2
  const float* bias = (sel == 0) ? bq : (sel == 1) ? bk : bv;

  f32x4 acc[4][2];
  #pragma unroll
  for (int mf = 0; mf < 4; ++mf)
    #pragma unroll
    for (int nf = 0; nf < 2; ++nf) acc[mf][nf] = (f32x4){0.f, 0.f, 0.f, 0.f};

  const int sr = lane >> 2;   // row within 16-row chunk
  const int sc = lane & 3;    // 16B slot within 64B row

#define STG(DST, SRC, TB, R0, KT)                                          \
  async16(&DST[(R0)][0],                                                   \
          &SRC[(size_t)((TB) + (R0) + sr) * 1024 + (KT) +                  \
               ((sc ^ ((((R0) + sr) >> 1) & 3)) << 3)]);

#define STAGE(B_, KT)                          \
  {                                            \
    STG(Ahs[B_], Ah, bm, w * 32, KT);          \
    STG(Ahs[B_], Ah, bm, w * 32 + 16, KT);     \
    STG(Bhs[B_], Bh, bnl, w * 16, KT);         \
    if (sel < 2) {                             \
      STG(Als[B_], Al, bm, w * 32, KT);        \
      STG(Als[B_], Al, bm, w * 32 + 16, KT);   \
      STG(Bls[B_], Bl, bnl, w * 16, KT);       \
    }                                          \
  }

  STAGE(0, 0);
  __syncthreads();

  const int fr = lane & 15;
  const int fg = lane >> 4;
  int cur = 0;

  for (int kt = 0; kt < 1024; kt += 32) {
    if (kt + 32 < 1024) STAGE(cur ^ 1, kt + 32);

    u16x8 a_h[4], b_h[2];
    #pragma unroll
    for (int mf = 0; mf < 4; ++mf) {
      const int row = wr * 64 + mf * 16 + fr;
      const int cs = (fg ^ ((row >> 1) & 3)) << 3;
      a_h[mf] = *(const u16x8*)&Ahs[cur][row][cs];
    }
    #pragma unroll
    for (int nf = 0; nf < 2; ++nf) {
      const int col = wc * 32 + nf * 16 + fr;
      const int cs = (fg ^ ((col >> 1) & 3)) << 3;
      b_h[nf] = *(const u16x8*)&Bhs[cur][col][cs];
    }

    if (sel < 2) {
      u16x8 a_l[4], b_l[2];
      #pragma unroll
      for (int mf = 0; mf < 4; ++mf) {
        const int row = wr * 64 + mf * 16 + fr;
        const int cs = (fg ^ ((row >> 1) & 3)) << 3;
        a_l[mf] = *(const u16x8*)&Als[cur][row][cs];
      }
      #pragma unroll
      for (int nf = 0; nf < 2; ++nf) {
        const int col = wc * 32 + nf * 16 + fr;
        const int cs = (fg ^ ((col >> 1) & 3)) << 3;
        b_l[nf] = *(const u16x8*)&Bls[cur][col][cs];
      }
      #pragma unroll
      for (int mf = 0; mf < 4; ++mf)
        #pragma unroll
        for (int nf = 0; nf < 2; ++nf) {
          acc[mf][nf] = __builtin_amdgcn_mfma_f32_16x16x32_bf16(a_h[mf], b_h[nf], acc[mf][nf], 0, 0, 0);
          acc[mf][nf] = __builtin_amdgcn_mfma_f32_16x16x32_bf16(a_h[mf], b_l[nf], acc[mf][nf], 0, 0, 0);
          acc[mf][nf] = __builtin_amdgcn_mfma_f32_16x16x32_bf16(a_l[mf], b_h[nf], acc[mf][nf], 0, 0, 0);
        }
    } else {
      #pragma unroll
      for (int mf = 0; mf < 4; ++mf)
        #pragma unroll
        for (int nf = 0; nf < 2; ++nf)
          acc[mf][nf] = __builtin_amdgcn_mfma_f32_16x16x32_bf16(a_h[mf], b_h[nf], acc[mf][nf], 0, 0, 0);
    }
    __syncthreads();
    cur ^= 1;
  }
#undef STAGE
#undef STG

  if (sel < 2) {
    const int c0 = bnl + wc * 32 + fr;
    const int c1 = c0 + 16;
    const float bb0 = bias[c0];
    const float bb1 = bias[c1];
    const int head = bnl >> 6;
    #pragma unroll
    for (int mf = 0; mf < 4; ++mf) {
      const int row0 = bm + wr * 64 + mf * 16;
      #pragma unroll
      for (int j = 0; j < 4; ++j) {
        const float v0 = acc[mf][0][j] + bb0;
        const float v1 = acc[mf][1][j] + bb1;
        const u64 b0 = __ballot(v0 > 1.0f);
        const u64 b1 = __ballot(v1 > 1.0f);
        const int m = row0 + fg * 4 + j;
        if (fr == 0) {
          const u32 mask = (u32)((b0 >> (fg * 16)) & 0xFFFFu)
                         | ((u32)((b1 >> (fg * 16)) & 0xFFFFu) << 16);
          pbits[(((size_t)sel * 4096 + m) * 16 + head) * 2 + wc] = mask;
        }
        if (__builtin_fabsf(v0 - 1.0f) < TAU) {
          const u32 s = atomicAdd(flagcnt, 1u);
          if (s < FCAP) flaglist[s] = ((u32)sel << 22) | ((u32)m << 10) | (u32)c0;
        }
        if (__builtin_fabsf(v1 - 1.0f) < TAU) {
          const u32 s = atomicAdd(flagcnt, 1u);
          if (s < FCAP) flaglist[s] = ((u32)sel << 22) | ((u32)m << 10) | (u32)c1;
        }
      }
    }
  } else {
    #pragma unroll
    for (int mf = 0; mf < 4; ++mf) {
      const int row0 = bm + wr * 64 + mf * 16 + fg * 4;
      #pragma unroll
      for (int nf = 0; nf < 2; ++nf) {
        const int col = bnl + wc * 32 + nf * 16 + fr;
        const float bb = bias[col];
        const int bb_ = row0 >> 11, t0 = row0 & 2047;
        const int hh = col >> 6, dd = col & 63;
        u16x4 o;
        o[0] = f2bf(acc[mf][nf][0] + bb);
        o[1] = f2bf(acc[mf][nf][1] + bb);
        o[2] = f2bf(acc[mf][nf][2] + bb);
        o[3] = f2bf(acc[mf][nf][3] + bb);
        *(u16x4*)&vT[(((size_t)(bb_ * 16 + hh)) * 64 + dd) * 2048 + t0] = o;
      }
    }
  }
}

// ---------------------------------------------------------------------------
// Recompute near-threshold q/k entries with exact fp32 dot; patch via
// atomicXor (verified).
// ---------------------------------------------------------------------------
__global__ __launch_bounds__(256) void fix_bits(
    const float* __restrict__ x,
    const float* __restrict__ Wq, const float* __restrict__ Wk,
    const float* __restrict__ bq, const float* __restrict__ bk,
    u32* __restrict__ pbits,
    const u32* __restrict__ flagcnt, const u32* __restrict__ flaglist)
{
  u32 cnt = *flagcnt;
  if (cnt > FCAP) cnt = FCAP;
  const int lane = threadIdx.x & 63;
  const u32 wid  = (blockIdx.x * 256 + threadIdx.x) >> 6;
  const u32 nw   = gridDim.x * 4;
  for (u32 i = wid; i < cnt; i += nw) {
    const u32 e = flaglist[i];
    const int which = e >> 22;
    const int m = (e >> 10) & 4095;
    const int n = e & 1023;
    const float* W    = which ? Wk : Wq;
    const float* bias = which ? bk : bq;
    float s = 0.f;
    #pragma unroll
    for (int j = 0; j < 16; ++j)
      s += x[(size_t)m * 1024 + lane + j * 64] * W[(size_t)n * 1024 + lane + j * 64];
    #pragma unroll
    for (int off = 32; off > 0; off >>= 1) s += __shfl_xor(s, off);
    const float val = s + bias[n];
    if (lane == 0) {
      const size_t idx = (((size_t)which * 4096 + m) * 16 + (n >> 6)) * 2 + ((n >> 5) & 1);
      const u32 bit = 1u << (n & 31);
      const bool oldb = (pbits[idx] >> (n & 31)) & 1u;
      const bool newb = val > 1.0f;
      if (oldb != newb) atomicXor(&pbits[idx], bit);
    }
  }
}

// ---------------------------------------------------------------------------
// MFMA attention (verified): per block = (bh, 64-query tile).
// Round 6: writes only bf16 oh (out-proj is single-pass now).
// ---------------------------------------------------------------------------
__global__ __launch_bounds__(256) void attn_mfma(
    const u32* __restrict__ pbits, const u16* __restrict__ vT,
    u16* __restrict__ oh)
{
  __shared__ u16 wtb[64][72];
  __shared__ u16 vtb[64][72];
  __shared__ u64 kbt[64];
  __shared__ float zred[256];
  __shared__ float zfin[64];

  const int tid = threadIdx.x, lane = tid & 63, w = tid >> 6;
  const int bid = blockIdx.x;
  const int qt = bid & 31, bh = bid >> 5, b = bh >> 4, h = bh & 15;

  const int qw = tid >> 2, ks0 = (tid & 3) << 4;
  const int qm = b * T_LEN + qt * 64 + qw;
  const size_t qbase = (((size_t)qm) * 16 + h) * 2;
  const u64 myqb = (u64)pbits[qbase] | ((u64)pbits[qbase + 1] << 32);
  float zacc = 0.f;

  f32x4 acc[4];
  #pragma unroll
  for (int nf = 0; nf < 4; ++nf) acc[nf] = (f32x4){0.f, 0.f, 0.f, 0.f};

  const u16* vbase = vT + (size_t)bh * 64 * T_LEN;
  const int sd = tid >> 2, sk = (tid & 3) << 3;
  const int fr = lane & 15, fg = lane >> 4;

  for (int kt = 0; kt < T_LEN; kt += 64) {
    *(u16x8*)&vtb[sd][sk]      = *(const u16x8*)&vbase[(size_t)sd * T_LEN + kt + sk];
    *(u16x8*)&vtb[sd][sk + 32] = *(const u16x8*)&vbase[(size_t)sd * T_LEN + kt + sk + 32];
    if (tid < 64) {
      const int km = b * T_LEN + kt + tid;
      const size_t kb = (((size_t)(4096 + km)) * 16 + h) * 2;
      kbt[tid] = (u64)pbits[kb] | ((u64)pbits[kb + 1] << 32);
    }
    __syncthreads();

    #pragma unroll
    for (int i = 0; i < 16; ++i) {
      const int kk = ks0 + i;
      const int mm = __popcll(myqb & kbt[kk]);
      const u16 wb = f2bf(__expf((float)mm * 0.125f));
      wtb[qw][kk] = wb;
      zacc += bf2f(wb);
    }
    __syncthreads();

    #pragma unroll
    for (int ks = 0; ks < 2; ++ks) {
      const u16x8 af = *(const u16x8*)&wtb[w * 16 + fr][ks * 32 + fg * 8];
      #pragma unroll
      for (int nf = 0; nf < 4; ++nf) {
        const u16x8 bfv = *(const u16x8*)&vtb[nf * 16 + fr][ks * 32 + fg * 8];
        acc[nf] = __builtin_amdgcn_mfma_f32_16x16x32_bf16(af, bfv, acc[nf], 0, 0, 0);
      }
    }
    __syncthreads();
  }

  zred[tid] = zacc;
  __syncthreads();
  if (tid < 64)
    zfin[tid] = zred[tid * 4] + zred[tid * 4 + 1] + zred[tid * 4 + 2] + zred[tid * 4 + 3];
  __syncthreads();

  #pragma unroll
  for (int nf = 0; nf < 4; ++nf) {
    const int col = h * 64 + nf * 16 + fr;
    #pragma unroll
    for (int j = 0; j < 4; ++j) {
      const int qrow = w * 16 + fg * 4 + j;
      const float o = acc[nf][j] / zfin[qrow];
      const size_t gq = (size_t)b * T_LEN + qt * 64 + qrow;
      oh[gq * 1024 + col] = f2bf(o);
    }
  }
}

// ---------------------------------------------------------------------------
// Out projection: single-pass bf16 MFMA (error ~1e-4 at output, safe),
// fp32 out + bias. Same swizzled gload_lds staging; 24KB LDS.
// ---------------------------------------------------------------------------
__global__ __launch_bounds__(256) void mfma_out(
    const u16* __restrict__ Ah, const u16* __restrict__ Bh,
    const float* __restrict__ bias, float* __restrict__ out)
{
  __shared__ u16 Ahs[2][128][32];
  __shared__ u16 Bhs[2][64][32];

  const int tid  = threadIdx.x;
  const int lane = tid & 63;
  const int w    = tid >> 6;
  const int wr   = w & 1;
  const int wc   = w >> 1;
  const int bm   = blockIdx.x * 128;
  const int bn   = blockIdx.y * 64;

  f32x4 acc[4][2];
  #pragma unroll
  for (int mf = 0; mf < 4; ++mf)
    #pragma unroll
    for (int nf = 0; nf < 2; ++nf) acc[mf][nf] = (f32x4){0.f, 0.f, 0.f, 0.f};

  const int sr = lane >> 2;
  const int sc = lane & 3;

#define STG(DST, SRC, TB, R0, KT)                                          \
  async16(&DST[(R0)][0],                                                   \
          &SRC[(size_t)((TB) + (R0) + sr) * 1024 + (KT) +                  \
               ((sc ^ ((((R0) + sr) >> 1) & 3)) << 3)]);

#define STAGE(B_, KT)                        \
  {                                          \
    STG(Ahs[B_], Ah, bm, w * 32, KT);        \
    STG(Ahs[B_], Ah, bm, w * 32 + 16, KT);   \
    STG(Bhs[B_], Bh, bn, w * 16, KT);        \
  }

  STAGE(0, 0);
  __syncthreads();

  const int fr = lane & 15;
  const int fg = lane >> 4;
  int cur = 0;

  for (int kt = 0; kt < 1024; kt += 32) {
    if (kt + 32 < 1024) STAGE(cur ^ 1, kt + 32);

    u16x8 a_h[4], b_h[2];
    #pragma unroll
    for (int mf = 0; mf < 4; ++mf) {
      const int row = wr * 64 + mf * 16 + fr;
      const int cs = (fg ^ ((row >> 1) & 3)) << 3;
      a_h[mf] = *(const u16x8*)&Ahs[cur][row][cs];
    }
    #pragma unroll
    for (int nf = 0; nf < 2; ++nf) {
      const int col = wc * 32 + nf * 16 + fr;
      const int cs = (fg ^ ((col >> 1) & 3)) << 3;
      b_h[nf] = *(const u16x8*)&Bhs[cur][col][cs];
    }
    #pragma unroll
    for (int mf = 0; mf < 4; ++mf)
      #pragma unroll
      for (int nf = 0; nf < 2; ++nf)
        acc[mf][nf] = __builtin_amdgcn_mfma_f32_16x16x32_bf16(a_h[mf], b_h[nf], acc[mf][nf], 0, 0, 0);
    __syncthreads();
    cur ^= 1;
  }
#undef STAGE
#undef STG

  #pragma unroll
  for (int mf = 0; mf < 4; ++mf) {
    const int row0 = bm + wr * 64 + mf * 16 + fg * 4;
    #pragma unroll
    for (int nf = 0; nf < 2; ++nf) {
      const int col = bn + wc * 32 + nf * 16 + fr;
      const float bb = bias[col];
      #pragma unroll
      for (int j = 0; j < 4; ++j)
        out[(size_t)(row0 + j) * 1024 + col] = acc[mf][nf][j] + bb;
    }
  }
}

// ---------------------------------------------------------------------------
extern "C" void kernel_launch(void* const* d_in, const int* in_sizes, int n_in,
                              void* d_out, int out_size, void* d_ws, size_t ws_size,
                              hipStream_t stream) {
  const float* x  = (const float*)d_in[0];
  const float* Wq = (const float*)d_in[1];
  const float* bq = (const float*)d_in[2];
  const float* Wk = (const float*)d_in[3];
  const float* bk = (const float*)d_in[4];
  const float* Wv = (const float*)d_in[5];
  const float* bv = (const float*)d_in[6];
  const float* Wo = (const float*)d_in[7];
  const float* bo = (const float*)d_in[8];
  float* out = (float*)d_out;

  char* ws = (char*)d_ws;
  u16* oh   = (u16*)ws;
  u16* ol   = (u16*)(ws + 8 * MB);     // unused since round 6
  u16* xh   = (u16*)(ws + 16 * MB);
  u16* xl   = (u16*)(ws + 24 * MB);
  u16* vT   = (u16*)(ws + 32 * MB);
  u16* Woh  = (u16*)(ws + 40 * MB);
  u16* Wol  = (u16*)(ws + 42 * MB);    // written, unused
  u32* pbits = (u32*)(ws + 44 * MB);
  u32* flagcnt  = (u32*)(ws + 45 * MB);
  u32* flaglist = (u32*)(ws + 45 * MB + 256);
  (void)ol;

  // d_out doubles as scratch for q/k/v weight splits (dead before out-proj).
  char* dob = (char*)d_out;
  u16* Wqh = (u16*)dob;
  u16* Wql = (u16*)(dob + 2 * MB);
  u16* Wkh = (u16*)(dob + 4 * MB);
  u16* Wkl = (u16*)(dob + 6 * MB);
  u16* Wvh = (u16*)(dob + 8 * MB);
  u16* Wvl = (u16*)(dob + 10 * MB);    // written, unused

  split_all<<<8192, 256, 0, stream>>>(x, Wq, Wk, Wv, Wo,
                                      xh, xl, Wqh, Wql, Wkh, Wkl,
                                      Wvh, Wvl, Woh, Wol, flagcnt);

  dim3 g1(M_ROWS / 128, 3072 / 64);
  mfma_qkv<<<g1, 256, 0, stream>>>(xh, xl, Wqh, Wql, Wkh, Wkl, Wvh,
                                   bq, bk, bv, pbits, flagcnt, flaglist, vT);

  fix_bits<<<64, 256, 0, stream>>>(x, Wq, Wk, bq, bk, pbits, flagcnt, flaglist);

  attn_mfma<<<32 * 32, 256, 0, stream>>>(pbits, vT, oh);

  dim3 g2(M_ROWS / 128, 1024 / 64);
  mfma_out<<<g2, 256, 0, stream>>>(oh, Woh, bo, out);
}

// Round 7
// 193.208 us; speedup vs baseline: 1.5447x; 1.0500x over previous
//
#include <hip/hip_runtime.h>
#include <cstdint>

typedef unsigned long long u64;
typedef unsigned int u32;
typedef unsigned short u16;
typedef __attribute__((ext_vector_type(8))) u16 u16x8;
typedef __attribute__((ext_vector_type(4))) u16 u16x4;
typedef __attribute__((ext_vector_type(4))) float f32x4;

#define T_LEN 2048
#define C_DIM 1024
#define H_NUM 16
#define M_ROWS 4096  // B*T
#define MB (1024ull * 1024ull)
#define TAU 2e-4f
#define FCAP 65536u

// bf16 helpers (manual RNE, finite inputs only)
__device__ __forceinline__ u16 f2bf(float f) {
  unsigned u = __builtin_bit_cast(unsigned, f);
  return (u16)((u + 0x7FFFu + ((u >> 16) & 1u)) >> 16);
}
__device__ __forceinline__ float bf2f(u16 u) {
  return __builtin_bit_cast(float, ((unsigned)u) << 16);
}

// async global->LDS, 16B/lane: LDS dest = wave-uniform base + lane*16,
// global src = per-lane pointer.
__device__ __forceinline__ void async16(u16* lds, const u16* g) {
  __builtin_amdgcn_global_load_lds(
      (const __attribute__((address_space(1))) void*)g,
      (__attribute__((address_space(3))) void*)lds, 16, 0, 0);
}

// ---------------------------------------------------------------------------
// Split fp32 -> (hi,lo) bf16 for x, Wq, Wk, Wv, Wo in one launch.
// ---------------------------------------------------------------------------
__global__ __launch_bounds__(256) void split_all(
    const float* __restrict__ x,  const float* __restrict__ Wq,
    const float* __restrict__ Wk, const float* __restrict__ Wv,
    const float* __restrict__ Wo,
    u16* xh, u16* xl, u16* wqh, u16* wql, u16* wkh, u16* wkl,
    u16* wvh, u16* wvl, u16* woh, u16* wol, u32* flagcnt)
{
  const int i = blockIdx.x * 256 + threadIdx.x;
  if (i == 0) *flagcnt = 0;
  const float* src; u16 *hi, *lo; int off;
  if      (i < 1048576) { src = x;  hi = xh;  lo = xl;  off = i; }
  else if (i < 1310720) { src = Wq; hi = wqh; lo = wql; off = i - 1048576; }
  else if (i < 1572864) { src = Wk; hi = wkh; lo = wkl; off = i - 1310720; }
  else if (i < 1835008) { src = Wv; hi = wvh; lo = wvl; off = i - 1572864; }
  else                  { src = Wo; hi = woh; lo = wol; off = i - 1835008; }
  const float4 v = ((const float4*)src)[off];
  u16x4 h, l;
  float t;
  t = v.x; h[0] = f2bf(t); l[0] = f2bf(t - bf2f(h[0]));
  t = v.y; h[1] = f2bf(t); l[1] = f2bf(t - bf2f(h[1]));
  t = v.z; h[2] = f2bf(t); l[2] = f2bf(t - bf2f(h[2]));
  t = v.w; h[3] = f2bf(t); l[3] = f2bf(t - bf2f(h[3]));
  ((u16x4*)hi)[off] = h;
  ((u16x4*)lo)[off] = l;
}

// ---------------------------------------------------------------------------
// Fused QKV MFMA GEMM over N=3072 (sel 0:q, 1:k, 2:v). Verified round 6.
// ---------------------------------------------------------------------------
__global__ __launch_bounds__(256) void mfma_qkv(
    const u16* __restrict__ Ah, const u16* __restrict__ Al,
    const u16* __restrict__ Bqh, const u16* __restrict__ Bql,
    const u16* __restrict__ Bkh, const u16* __restrict__ Bkl,
    const u16* __restrict__ Bvh,
    const float* __restrict__ bq, const float* __restrict__ bk,
    const float* __restrict__ bv,
    u32* __restrict__ pbits, u32* __restrict__ flagcnt,
    u32* __restrict__ flaglist, u16* __restrict__ vT)
{
  __shared__ u16 Ahs[2][128][32];
  __shared__ u16 Als[2][128][32];
  __shared__ u16 Bhs[2][64][32];
  __shared__ u16 Bls[2][64][32];

  const int tid  = threadIdx.x;
  const int lane = tid & 63;
  const int w    = tid >> 6;
  const int wr   = w & 1;
  const int wc   = w >> 1;
  const int bm   = blockIdx.x * 128;
  const int bng  = blockIdx.y * 64;
  const int sel  = bng >> 10;
  const int bnl  = bng & 1023;

  const u16* Bh   = (sel == 0) ? Bqh : (sel == 1) ? Bkh : Bvh;
  const u16* Bl   = (sel == 0) ? Bql : Bkl;   // unused when sel==2
  const float* bias = (sel == 0) ? bq : (sel == 1) ? bk : bv;

  f32x4 acc[4][2];
  #pragma unroll
  for (int mf = 0; mf < 4; ++mf)
    #pragma unroll
    for (int nf = 0; nf < 2; ++nf) acc[mf][nf] = (f32x4){0.f, 0.f, 0.f, 0.f};

  const int sr = lane >> 2;
  const int sc = lane & 3;

#define STG(DST, SRC, TB, R0, KT)                                          \
  async16(&DST[(R0)][0],                                                   \
          &SRC[(size_t)((TB) + (R0) + sr) * 1024 + (KT) +                  \
               ((sc ^ ((((R0) + sr) >> 1) & 3)) << 3)]);

#define STAGE(B_, KT)                          \
  {                                            \
    STG(Ahs[B_], Ah, bm, w * 32, KT);          \
    STG(Ahs[B_], Ah, bm, w * 32 + 16, KT);     \
    STG(Bhs[B_], Bh, bnl, w * 16, KT);         \
    if (sel < 2) {                             \
      STG(Als[B_], Al, bm, w * 32, KT);        \
      STG(Als[B_], Al, bm, w * 32 + 16, KT);   \
      STG(Bls[B_], Bl, bnl, w * 16, KT);       \
    }                                          \
  }

  STAGE(0, 0);
  __syncthreads();

  const int fr = lane & 15;
  const int fg = lane >> 4;
  int cur = 0;

  for (int kt = 0; kt < 1024; kt += 32) {
    if (kt + 32 < 1024) STAGE(cur ^ 1, kt + 32);

    u16x8 a_h[4], b_h[2];
    #pragma unroll
    for (int mf = 0; mf < 4; ++mf) {
      const int row = wr * 64 + mf * 16 + fr;
      const int cs = (fg ^ ((row >> 1) & 3)) << 3;
      a_h[mf] = *(const u16x8*)&Ahs[cur][row][cs];
    }
    #pragma unroll
    for (int nf = 0; nf < 2; ++nf) {
      const int col = wc * 32 + nf * 16 + fr;
      const int cs = (fg ^ ((col >> 1) & 3)) << 3;
      b_h[nf] = *(const u16x8*)&Bhs[cur][col][cs];
    }

    if (sel < 2) {
      u16x8 a_l[4], b_l[2];
      #pragma unroll
      for (int mf = 0; mf < 4; ++mf) {
        const int row = wr * 64 + mf * 16 + fr;
        const int cs = (fg ^ ((row >> 1) & 3)) << 3;
        a_l[mf] = *(const u16x8*)&Als[cur][row][cs];
      }
      #pragma unroll
      for (int nf = 0; nf < 2; ++nf) {
        const int col = wc * 32 + nf * 16 + fr;
        const int cs = (fg ^ ((col >> 1) & 3)) << 3;
        b_l[nf] = *(const u16x8*)&Bls[cur][col][cs];
      }
      #pragma unroll
      for (int mf = 0; mf < 4; ++mf)
        #pragma unroll
        for (int nf = 0; nf < 2; ++nf) {
          acc[mf][nf] = __builtin_amdgcn_mfma_f32_16x16x32_bf16(a_h[mf], b_h[nf], acc[mf][nf], 0, 0, 0);
          acc[mf][nf] = __builtin_amdgcn_mfma_f32_16x16x32_bf16(a_h[mf], b_l[nf], acc[mf][nf], 0, 0, 0);
          acc[mf][nf] = __builtin_amdgcn_mfma_f32_16x16x32_bf16(a_l[mf], b_h[nf], acc[mf][nf], 0, 0, 0);
        }
    } else {
      #pragma unroll
      for (int mf = 0; mf < 4; ++mf)
        #pragma unroll
        for (int nf = 0; nf < 2; ++nf)
          acc[mf][nf] = __builtin_amdgcn_mfma_f32_16x16x32_bf16(a_h[mf], b_h[nf], acc[mf][nf], 0, 0, 0);
    }
    __syncthreads();
    cur ^= 1;
  }
#undef STAGE
#undef STG

  if (sel < 2) {
    const int c0 = bnl + wc * 32 + fr;
    const int c1 = c0 + 16;
    const float bb0 = bias[c0];
    const float bb1 = bias[c1];
    const int head = bnl >> 6;
    #pragma unroll
    for (int mf = 0; mf < 4; ++mf) {
      const int row0 = bm + wr * 64 + mf * 16;
      #pragma unroll
      for (int j = 0; j < 4; ++j) {
        const float v0 = acc[mf][0][j] + bb0;
        const float v1 = acc[mf][1][j] + bb1;
        const u64 b0 = __ballot(v0 > 1.0f);
        const u64 b1 = __ballot(v1 > 1.0f);
        const int m = row0 + fg * 4 + j;
        if (fr == 0) {
          const u32 mask = (u32)((b0 >> (fg * 16)) & 0xFFFFu)
                         | ((u32)((b1 >> (fg * 16)) & 0xFFFFu) << 16);
          pbits[(((size_t)sel * 4096 + m) * 16 + head) * 2 + wc] = mask;
        }
        if (__builtin_fabsf(v0 - 1.0f) < TAU) {
          const u32 s = atomicAdd(flagcnt, 1u);
          if (s < FCAP) flaglist[s] = ((u32)sel << 22) | ((u32)m << 10) | (u32)c0;
        }
        if (__builtin_fabsf(v1 - 1.0f) < TAU) {
          const u32 s = atomicAdd(flagcnt, 1u);
          if (s < FCAP) flaglist[s] = ((u32)sel << 22) | ((u32)m << 10) | (u32)c1;
        }
      }
    }
  } else {
    #pragma unroll
    for (int mf = 0; mf < 4; ++mf) {
      const int row0 = bm + wr * 64 + mf * 16 + fg * 4;
      #pragma unroll
      for (int nf = 0; nf < 2; ++nf) {
        const int col = bnl + wc * 32 + nf * 16 + fr;
        const float bb = bias[col];
        const int bb_ = row0 >> 11, t0 = row0 & 2047;
        const int hh = col >> 6, dd = col & 63;
        u16x4 o;
        o[0] = f2bf(acc[mf][nf][0] + bb);
        o[1] = f2bf(acc[mf][nf][1] + bb);
        o[2] = f2bf(acc[mf][nf][2] + bb);
        o[3] = f2bf(acc[mf][nf][3] + bb);
        *(u16x4*)&vT[(((size_t)(bb_ * 16 + hh)) * 64 + dd) * 2048 + t0] = o;
      }
    }
  }
}

// ---------------------------------------------------------------------------
// Recompute near-threshold q/k entries with exact fp32 dot; patch via
// atomicXor (verified).
// ---------------------------------------------------------------------------
__global__ __launch_bounds__(256) void fix_bits(
    const float* __restrict__ x,
    const float* __restrict__ Wq, const float* __restrict__ Wk,
    const float* __restrict__ bq, const float* __restrict__ bk,
    u32* __restrict__ pbits,
    const u32* __restrict__ flagcnt, const u32* __restrict__ flaglist)
{
  u32 cnt = *flagcnt;
  if (cnt > FCAP) cnt = FCAP;
  const int lane = threadIdx.x & 63;
  const u32 wid  = (blockIdx.x * 256 + threadIdx.x) >> 6;
  const u32 nw   = gridDim.x * 4;
  for (u32 i = wid; i < cnt; i += nw) {
    const u32 e = flaglist[i];
    const int which = e >> 22;
    const int m = (e >> 10) & 4095;
    const int n = e & 1023;
    const float* W    = which ? Wk : Wq;
    const float* bias = which ? bk : bq;
    float s = 0.f;
    #pragma unroll
    for (int j = 0; j < 16; ++j)
      s += x[(size_t)m * 1024 + lane + j * 64] * W[(size_t)n * 1024 + lane + j * 64];
    #pragma unroll
    for (int off = 32; off > 0; off >>= 1) s += __shfl_xor(s, off);
    const float val = s + bias[n];
    if (lane == 0) {
      const size_t idx = (((size_t)which * 4096 + m) * 16 + (n >> 6)) * 2 + ((n >> 5) & 1);
      const u32 bit = 1u << (n & 31);
      const bool oldb = (pbits[idx] >> (n & 31)) & 1u;
      const bool newb = val > 1.0f;
      if (oldb != newb) atomicXor(&pbits[idx], bit);
    }
  }
}

// ---------------------------------------------------------------------------
// MFMA attention, round 7:
//  - kbt padded [68] (idx kk + kk/16): weight-phase reads conflict-free
//  - weight pairs: u32-half popcounts, exp2f, truncation-pack, 1 b32 write
//  - Z via ones-column MFMA on the already-loaded A-frag (no LDS reduction)
//  - XCD-swizzled bid (same-bh q-tiles share an XCD L2 for vT)
//  - setprio around the PV MFMA cluster
// ---------------------------------------------------------------------------
__global__ __launch_bounds__(256) void attn_mfma(
    const u32* __restrict__ pbits, const u16* __restrict__ vT,
    u16* __restrict__ oh)
{
  __shared__ u16 wtb[64][72];
  __shared__ u16 vtb[64][72];
  __shared__ u64 kbt[68];

  const int tid = threadIdx.x, lane = tid & 63, w = tid >> 6;
  const int bid = ((blockIdx.x & 7) << 7) | (blockIdx.x >> 3);  // XCD swizzle
  const int qt = bid & 31, bh = bid >> 5, b = bh >> 4, h = bh & 15;

  const int qw = tid >> 2;
  const int g  = tid & 3;           // k-slice 16g..16g+15
  const int kbase = 17 * g;         // padded kbt base
  const int qm = b * T_LEN + qt * 64 + qw;
  const size_t qbase = (((size_t)qm) * 16 + h) * 2;
  const u32 qlo = pbits[qbase];
  const u32 qhi = pbits[qbase + 1];

  f32x4 acc[4];
  #pragma unroll
  for (int nf = 0; nf < 4; ++nf) acc[nf] = (f32x4){0.f, 0.f, 0.f, 0.f};
  f32x4 acc_z = (f32x4){0.f, 0.f, 0.f, 0.f};

  u16x8 ones;
  #pragma unroll
  for (int j = 0; j < 8; ++j) ones[j] = 0x3F80;  // bf16 1.0

  const u16* vbase = vT + (size_t)bh * 64 * T_LEN;
  const int sd = tid >> 2, sk = (tid & 3) << 3;
  const int fr = lane & 15, fg = lane >> 4;

  for (int kt = 0; kt < T_LEN; kt += 64) {
    *(u16x8*)&vtb[sd][sk]      = *(const u16x8*)&vbase[(size_t)sd * T_LEN + kt + sk];
    *(u16x8*)&vtb[sd][sk + 32] = *(const u16x8*)&vbase[(size_t)sd * T_LEN + kt + sk + 32];
    if (tid < 64) {
      const int km = b * T_LEN + kt + tid;
      const size_t kb = (((size_t)(4096 + km)) * 16 + h) * 2;
      kbt[tid + (tid >> 4)] = (u64)pbits[kb] | ((u64)pbits[kb + 1] << 32);
    }
    __syncthreads();

    // weights: 16 per thread, pair-packed truncated bf16
    #pragma unroll
    for (int i = 0; i < 16; i += 2) {
      const u64 kb0 = kbt[kbase + i];
      const u64 kb1 = kbt[kbase + i + 1];
      const int mm0 = __builtin_popcount(qlo & (u32)kb0)
                    + __builtin_popcount(qhi & (u32)(kb0 >> 32));
      const int mm1 = __builtin_popcount(qlo & (u32)kb1)
                    + __builtin_popcount(qhi & (u32)(kb1 >> 32));
      const u32 u0 = __builtin_bit_cast(u32, exp2f((float)mm0 * 0.1803368801f));
      const u32 u1 = __builtin_bit_cast(u32, exp2f((float)mm1 * 0.1803368801f));
      *(u32*)&wtb[qw][g * 16 + i] = (u1 & 0xFFFF0000u) | (u0 >> 16);
    }
    __syncthreads();

    __builtin_amdgcn_s_setprio(1);
    #pragma unroll
    for (int ks = 0; ks < 2; ++ks) {
      const u16x8 af = *(const u16x8*)&wtb[w * 16 + fr][ks * 32 + fg * 8];
      #pragma unroll
      for (int nf = 0; nf < 4; ++nf) {
        const u16x8 bfv = *(const u16x8*)&vtb[nf * 16 + fr][ks * 32 + fg * 8];
        acc[nf] = __builtin_amdgcn_mfma_f32_16x16x32_bf16(af, bfv, acc[nf], 0, 0, 0);
      }
      acc_z = __builtin_amdgcn_mfma_f32_16x16x32_bf16(af, ones, acc_z, 0, 0, 0);
    }
    __builtin_amdgcn_s_setprio(0);
    __syncthreads();
  }

  float invZ[4];
  #pragma unroll
  for (int j = 0; j < 4; ++j) invZ[j] = 1.0f / acc_z[j];

  #pragma unroll
  for (int nf = 0; nf < 4; ++nf) {
    const int col = h * 64 + nf * 16 + fr;
    #pragma unroll
    for (int j = 0; j < 4; ++j) {
      const int qrow = w * 16 + fg * 4 + j;
      const float o = acc[nf][j] * invZ[j];
      const size_t gq = (size_t)b * T_LEN + qt * 64 + qrow;
      oh[gq * 1024 + col] = f2bf(o);
    }
  }
}

// ---------------------------------------------------------------------------
// Out projection: single-pass bf16 MFMA (verified round 6).
// ---------------------------------------------------------------------------
__global__ __launch_bounds__(256) void mfma_out(
    const u16* __restrict__ Ah, const u16* __restrict__ Bh,
    const float* __restrict__ bias, float* __restrict__ out)
{
  __shared__ u16 Ahs[2][128][32];
  __shared__ u16 Bhs[2][64][32];

  const int tid  = threadIdx.x;
  const int lane = tid & 63;
  const int w    = tid >> 6;
  const int wr   = w & 1;
  const int wc   = w >> 1;
  const int bm   = blockIdx.x * 128;
  const int bn   = blockIdx.y * 64;

  f32x4 acc[4][2];
  #pragma unroll
  for (int mf = 0; mf < 4; ++mf)
    #pragma unroll
    for (int nf = 0; nf < 2; ++nf) acc[mf][nf] = (f32x4){0.f, 0.f, 0.f, 0.f};

  const int sr = lane >> 2;
  const int sc = lane & 3;

#define STG(DST, SRC, TB, R0, KT)                                          \
  async16(&DST[(R0)][0],                                                   \
          &SRC[(size_t)((TB) + (R0) + sr) * 1024 + (KT) +                  \
               ((sc ^ ((((R0) + sr) >> 1) & 3)) << 3)]);

#define STAGE(B_, KT)                        \
  {                                          \
    STG(Ahs[B_], Ah, bm, w * 32, KT);        \
    STG(Ahs[B_], Ah, bm, w * 32 + 16, KT);   \
    STG(Bhs[B_], Bh, bn, w * 16, KT);        \
  }

  STAGE(0, 0);
  __syncthreads();

  const int fr = lane & 15;
  const int fg = lane >> 4;
  int cur = 0;

  for (int kt = 0; kt < 1024; kt += 32) {
    if (kt + 32 < 1024) STAGE(cur ^ 1, kt + 32);

    u16x8 a_h[4], b_h[2];
    #pragma unroll
    for (int mf = 0; mf < 4; ++mf) {
      const int row = wr * 64 + mf * 16 + fr;
      const int cs = (fg ^ ((row >> 1) & 3)) << 3;
      a_h[mf] = *(const u16x8*)&Ahs[cur][row][cs];
    }
    #pragma unroll
    for (int nf = 0; nf < 2; ++nf) {
      const int col = wc * 32 + nf * 16 + fr;
      const int cs = (fg ^ ((col >> 1) & 3)) << 3;
      b_h[nf] = *(const u16x8*)&Bhs[cur][col][cs];
    }
    #pragma unroll
    for (int mf = 0; mf < 4; ++mf)
      #pragma unroll
      for (int nf = 0; nf < 2; ++nf)
        acc[mf][nf] = __builtin_amdgcn_mfma_f32_16x16x32_bf16(a_h[mf], b_h[nf], acc[mf][nf], 0, 0, 0);
    __syncthreads();
    cur ^= 1;
  }
#undef STAGE
#undef STG

  #pragma unroll
  for (int mf = 0; mf < 4; ++mf) {
    const int row0 = bm + wr * 64 + mf * 16 + fg * 4;
    #pragma unroll
    for (int nf = 0; nf < 2; ++nf) {
      const int col = bn + wc * 32 + nf * 16 + fr;
      const float bb = bias[col];
      #pragma unroll
      for (int j = 0; j < 4; ++j)
        out[(size_t)(row0 + j) * 1024 + col] = acc[mf][nf][j] + bb;
    }
  }
}

// ---------------------------------------------------------------------------
extern "C" void kernel_launch(void* const* d_in, const int* in_sizes, int n_in,
                              void* d_out, int out_size, void* d_ws, size_t ws_size,
                              hipStream_t stream) {
  const float* x  = (const float*)d_in[0];
  const float* Wq = (const float*)d_in[1];
  const float* bq = (const float*)d_in[2];
  const float* Wk = (const float*)d_in[3];
  const float* bk = (const float*)d_in[4];
  const float* Wv = (const float*)d_in[5];
  const float* bv = (const float*)d_in[6];
  const float* Wo = (const float*)d_in[7];
  const float* bo = (const float*)d_in[8];
  float* out = (float*)d_out;

  char* ws = (char*)d_ws;
  u16* oh   = (u16*)ws;
  u16* ol   = (u16*)(ws + 8 * MB);     // unused
  u16* xh   = (u16*)(ws + 16 * MB);
  u16* xl   = (u16*)(ws + 24 * MB);
  u16* vT   = (u16*)(ws + 32 * MB);
  u16* Woh  = (u16*)(ws + 40 * MB);
  u16* Wol  = (u16*)(ws + 42 * MB);    // written, unused
  u32* pbits = (u32*)(ws + 44 * MB);
  u32* flagcnt  = (u32*)(ws + 45 * MB);
  u32* flaglist = (u32*)(ws + 45 * MB + 256);
  (void)ol;

  // d_out doubles as scratch for q/k/v weight splits (dead before out-proj).
  char* dob = (char*)d_out;
  u16* Wqh = (u16*)dob;
  u16* Wql = (u16*)(dob + 2 * MB);
  u16* Wkh = (u16*)(dob + 4 * MB);
  u16* Wkl = (u16*)(dob + 6 * MB);
  u16* Wvh = (u16*)(dob + 8 * MB);
  u16* Wvl = (u16*)(dob + 10 * MB);    // written, unused

  split_all<<<8192, 256, 0, stream>>>(x, Wq, Wk, Wv, Wo,
                                      xh, xl, Wqh, Wql, Wkh, Wkl,
                                      Wvh, Wvl, Woh, Wol, flagcnt);

  dim3 g1(M_ROWS / 128, 3072 / 64);
  mfma_qkv<<<g1, 256, 0, stream>>>(xh, xl, Wqh, Wql, Wkh, Wkl, Wvh,
                                   bq, bk, bv, pbits, flagcnt, flaglist, vT);

  fix_bits<<<64, 256, 0, stream>>>(x, Wq, Wk, bq, bk, pbits, flagcnt, flaglist);

  attn_mfma<<<32 * 32, 256, 0, stream>>>(pbits, vT, oh);

  dim3 g2(M_ROWS / 128, 1024 / 64);
  mfma_out<<<g2, 256, 0, stream>>>(oh, Woh, bo, out);
}